// Round 6
// baseline (67082.336 us; speedup 1.0000x reference)
//
#include <hip/hip_runtime.h>

// ---------------------------------------------------------------------------
// Small-tile batched GEMM (64x64): C_z[M,N] = act(op(A_z) @ op(B_z) + bias + accum*C)
// 256 threads, 4x4 register tile, K-tile 16, double-buffered LDS.
// AL=true: all tile edges full (M%64==0, N%64==0, K%16==0) -> no bounds checks.
// Deterministic: per-output accumulation is single-thread, K-ascending.
// ---------------------------------------------------------------------------
template<bool AL>
__global__ __launch_bounds__(256, 4)
void gemm_kernel64(const float* __restrict__ A, int lda, int transA, long sA,
                   const float* __restrict__ B, int ldb, int transB, long sB,
                   const float* __restrict__ bias,
                   float* __restrict__ C, int ldc, long sC,
                   int M, int N, int K, int act, int accum)
{
    __shared__ __align__(16) float As[2][16][68];
    __shared__ __align__(16) float Bs[2][16][68];
    {
        const long z = blockIdx.z;
        A += z * sA; B += z * sB; C += z * sC;
    }
    const int tid = threadIdx.x;
    const int bm = blockIdx.y * 64;
    const int bn = blockIdx.x * 64;
    const int tr = tid >> 4, tc = tid & 15;
    float acc[4][4] = {};
    const int nt = (K + 15) / 16;
    float4 ra, rb;

    auto g_load = [&](int t) {
        const int k0 = t * 16;
        if (!transA) {
            int m = tid >> 2, kc = (tid & 3) * 4;
            if (AL) ra = *(const float4*)(A + (long)(bm + m) * lda + k0 + kc);
            else {
                float4 v = {0.f, 0.f, 0.f, 0.f};
                if (bm + m < M) {
                    const float* ap = A + (long)(bm + m) * lda + k0 + kc;
                    if (k0 + kc + 3 < K) v = *(const float4*)ap;
                    else { float t4[4] = {0.f,0.f,0.f,0.f};
                           for (int q = 0; q < 4; ++q) if (k0 + kc + q < K) t4[q] = ap[q];
                           v = *(float4*)t4; }
                }
                ra = v;
            }
        } else {
            int kk = tid >> 4, mc = (tid & 15) * 4;
            if (AL) ra = *(const float4*)(A + (long)(k0 + kk) * lda + bm + mc);
            else {
                float4 v = {0.f, 0.f, 0.f, 0.f};
                if (k0 + kk < K) {
                    const float* ap = A + (long)(k0 + kk) * lda + bm + mc;
                    if (bm + mc + 3 < M) v = *(const float4*)ap;
                    else { float t4[4] = {0.f,0.f,0.f,0.f};
                           for (int q = 0; q < 4; ++q) if (bm + mc + q < M) t4[q] = ap[q];
                           v = *(float4*)t4; }
                }
                ra = v;
            }
        }
        if (!transB) {
            int kk = tid >> 4, nc = (tid & 15) * 4;
            if (AL) rb = *(const float4*)(B + (long)(k0 + kk) * ldb + bn + nc);
            else {
                float4 v = {0.f, 0.f, 0.f, 0.f};
                if (k0 + kk < K) {
                    const float* bp = B + (long)(k0 + kk) * ldb + bn + nc;
                    if (bn + nc + 3 < N) v = *(const float4*)bp;
                    else { float t4[4] = {0.f,0.f,0.f,0.f};
                           for (int q = 0; q < 4; ++q) if (bn + nc + q < N) t4[q] = bp[q];
                           v = *(float4*)t4; }
                }
                rb = v;
            }
        } else {
            int n = tid >> 2, kc = (tid & 3) * 4;
            if (AL) rb = *(const float4*)(B + (long)(bn + n) * ldb + k0 + kc);
            else {
                float4 v = {0.f, 0.f, 0.f, 0.f};
                if (bn + n < N) {
                    const float* bp = B + (long)(bn + n) * ldb + k0 + kc;
                    if (k0 + kc + 3 < K) v = *(const float4*)bp;
                    else { float t4[4] = {0.f,0.f,0.f,0.f};
                           for (int q = 0; q < 4; ++q) if (k0 + kc + q < K) t4[q] = bp[q];
                           v = *(float4*)t4; }
                }
                rb = v;
            }
        }
    };
    auto s_store = [&](int buf) {
        if (!transA) {
            int m = tid >> 2, kc = (tid & 3) * 4;
            As[buf][kc + 0][m] = ra.x; As[buf][kc + 1][m] = ra.y;
            As[buf][kc + 2][m] = ra.z; As[buf][kc + 3][m] = ra.w;
        } else {
            int kk = tid >> 4, mc = (tid & 15) * 4;
            *(float4*)&As[buf][kk][mc] = ra;
        }
        if (!transB) {
            int kk = tid >> 4, nc = (tid & 15) * 4;
            *(float4*)&Bs[buf][kk][nc] = rb;
        } else {
            int n = tid >> 2, kc = (tid & 3) * 4;
            Bs[buf][kc + 0][n] = rb.x; Bs[buf][kc + 1][n] = rb.y;
            Bs[buf][kc + 2][n] = rb.z; Bs[buf][kc + 3][n] = rb.w;
        }
    };

    g_load(0); s_store(0);
    __syncthreads();
    for (int t = 0; t < nt; ++t) {
        const int cur = t & 1;
        if (t + 1 < nt) g_load(t + 1);
        #pragma unroll
        for (int kk = 0; kk < 16; ++kk) {
            const float4 b4 = *(const float4*)&Bs[cur][kk][tc * 4];
            const float4 a4 = *(const float4*)&As[cur][kk][tr * 4];
            const float bb[4] = {b4.x, b4.y, b4.z, b4.w};
            const float aa[4] = {a4.x, a4.y, a4.z, a4.w};
            #pragma unroll
            for (int im = 0; im < 4; ++im)
                #pragma unroll
                for (int in = 0; in < 4; ++in)
                    acc[im][in] += aa[im] * bb[in];
        }
        if (t + 1 < nt) s_store(cur ^ 1);
        __syncthreads();
    }
    #pragma unroll
    for (int im = 0; im < 4; ++im) {
        int m = bm + tr * 4 + im;
        if (!AL && m >= M) continue;
        #pragma unroll
        for (int in = 0; in < 4; ++in) {
            int n = bn + tc * 4 + in;
            if (!AL && n >= N) continue;
            float v = acc[im][in];
            if (bias) v += bias[n];
            if (accum) v += C[(long)m * ldc + n];
            if (act) v = fmaxf(v, 0.f);
            C[(long)m * ldc + n] = v;
        }
    }
}

// ---------------------------------------------------------------------------
// Big-tile GEMM: 128x128 C-tile, 256 threads, 8x8 register tile, K-tile 16,
// double-buffered LDS. No manual fragment prefetch (compiler pipelines
// ds_read->FMA with fine-grained lgkmcnt); __launch_bounds__(256,3) caps
// VGPRs for 3 waves/SIMD. Fragment reads split {x*4, 64+x*4}: 2-way bank
// aliasing only (free). Accumulation order per output: K-ascending, single
// thread — bitwise identical to gemm_kernel64.
// ---------------------------------------------------------------------------
template<bool AL>
__global__ __launch_bounds__(256, 3)
void gemm_kernel128(const float* __restrict__ A, int lda, int transA, long sA,
                    const float* __restrict__ B, int ldb, int transB, long sB,
                    const float* __restrict__ bias,
                    float* __restrict__ C, int ldc, long sC,
                    int M, int N, int K, int act, int accum)
{
    __shared__ __align__(16) float As[2][16][132];
    __shared__ __align__(16) float Bs[2][16][132];
    {
        const long z = blockIdx.z;
        A += z * sA; B += z * sB; C += z * sC;
    }
    const int tid = threadIdx.x;
    const int bm = blockIdx.y * 128;
    const int bn = blockIdx.x * 128;
    const int tx = tid & 15, ty = tid >> 4;
    float acc[8][8] = {};
    const int nt = (K + 15) / 16;
    float4 ra[2], rb[2];

    auto g_load = [&](int t) {
        const int k0 = t * 16;
        #pragma unroll
        for (int j = 0; j < 2; ++j) {
            int idx = tid + j * 256;
            if (!transA) {
                int m = idx >> 2, kc = (idx & 3) * 4;
                if (AL) ra[j] = *(const float4*)(A + (long)(bm + m) * lda + k0 + kc);
                else {
                    float4 v = {0.f, 0.f, 0.f, 0.f};
                    if (bm + m < M) {
                        const float* ap = A + (long)(bm + m) * lda + k0 + kc;
                        if (k0 + kc + 3 < K) v = *(const float4*)ap;
                        else { float t4[4] = {0.f,0.f,0.f,0.f};
                               for (int q = 0; q < 4; ++q) if (k0 + kc + q < K) t4[q] = ap[q];
                               v = *(float4*)t4; }
                    }
                    ra[j] = v;
                }
            } else {
                int kk = idx >> 5, mc = (idx & 31) * 4;
                if (AL) ra[j] = *(const float4*)(A + (long)(k0 + kk) * lda + bm + mc);
                else {
                    float4 v = {0.f, 0.f, 0.f, 0.f};
                    if (k0 + kk < K) {
                        const float* ap = A + (long)(k0 + kk) * lda + bm + mc;
                        if (bm + mc + 3 < M) v = *(const float4*)ap;
                        else { float t4[4] = {0.f,0.f,0.f,0.f};
                               for (int q = 0; q < 4; ++q) if (bm + mc + q < M) t4[q] = ap[q];
                               v = *(float4*)t4; }
                    }
                    ra[j] = v;
                }
            }
            if (!transB) {
                int kk = idx >> 5, nc = (idx & 31) * 4;
                if (AL) rb[j] = *(const float4*)(B + (long)(k0 + kk) * ldb + bn + nc);
                else {
                    float4 v = {0.f, 0.f, 0.f, 0.f};
                    if (k0 + kk < K) {
                        const float* bp = B + (long)(k0 + kk) * ldb + bn + nc;
                        if (bn + nc + 3 < N) v = *(const float4*)bp;
                        else { float t4[4] = {0.f,0.f,0.f,0.f};
                               for (int q = 0; q < 4; ++q) if (bn + nc + q < N) t4[q] = bp[q];
                               v = *(float4*)t4; }
                    }
                    rb[j] = v;
                }
            } else {
                int n = idx >> 2, kc = (idx & 3) * 4;
                if (AL) rb[j] = *(const float4*)(B + (long)(bn + n) * ldb + k0 + kc);
                else {
                    float4 v = {0.f, 0.f, 0.f, 0.f};
                    if (bn + n < N) {
                        const float* bp = B + (long)(bn + n) * ldb + k0 + kc;
                        if (k0 + kc + 3 < K) v = *(const float4*)bp;
                        else { float t4[4] = {0.f,0.f,0.f,0.f};
                               for (int q = 0; q < 4; ++q) if (k0 + kc + q < K) t4[q] = bp[q];
                               v = *(float4*)t4; }
                    }
                    rb[j] = v;
                }
            }
        }
    };
    auto s_store = [&](int buf) {
        #pragma unroll
        for (int j = 0; j < 2; ++j) {
            int idx = tid + j * 256;
            if (!transA) {
                int m = idx >> 2, kc = (idx & 3) * 4;
                As[buf][kc + 0][m] = ra[j].x; As[buf][kc + 1][m] = ra[j].y;
                As[buf][kc + 2][m] = ra[j].z; As[buf][kc + 3][m] = ra[j].w;
            } else {
                int kk = idx >> 5, mc = (idx & 31) * 4;
                *(float4*)&As[buf][kk][mc] = ra[j];
            }
            if (!transB) {
                int kk = idx >> 5, nc = (idx & 31) * 4;
                *(float4*)&Bs[buf][kk][nc] = rb[j];
            } else {
                int n = idx >> 2, kc = (idx & 3) * 4;
                Bs[buf][kc + 0][n] = rb[j].x; Bs[buf][kc + 1][n] = rb[j].y;
                Bs[buf][kc + 2][n] = rb[j].z; Bs[buf][kc + 3][n] = rb[j].w;
            }
        }
    };

    g_load(0); s_store(0);
    __syncthreads();
    for (int t = 0; t < nt; ++t) {
        const int cur = t & 1;
        if (t + 1 < nt) g_load(t + 1);
        #pragma unroll
        for (int kk = 0; kk < 16; ++kk) {
            const float4 a0 = *(const float4*)&As[cur][kk][ty * 4];
            const float4 a1 = *(const float4*)&As[cur][kk][64 + ty * 4];
            const float4 b0 = *(const float4*)&Bs[cur][kk][tx * 4];
            const float4 b1 = *(const float4*)&Bs[cur][kk][64 + tx * 4];
            const float aa[8] = {a0.x, a0.y, a0.z, a0.w, a1.x, a1.y, a1.z, a1.w};
            const float bb[8] = {b0.x, b0.y, b0.z, b0.w, b1.x, b1.y, b1.z, b1.w};
            #pragma unroll
            for (int im = 0; im < 8; ++im)
                #pragma unroll
                for (int in = 0; in < 8; ++in)
                    acc[im][in] += aa[im] * bb[in];
        }
        if (t + 1 < nt) s_store(cur ^ 1);
        __syncthreads();
    }
    #pragma unroll
    for (int im = 0; im < 8; ++im) {
        int m = bm + (im < 4 ? ty * 4 + im : 64 + ty * 4 + im - 4);
        if (!AL && m >= M) continue;
        #pragma unroll
        for (int in = 0; in < 8; ++in) {
            int n = bn + (in < 4 ? tx * 4 + in : 64 + tx * 4 + in - 4);
            if (!AL && n >= N) continue;
            float v = acc[im][in];
            if (bias) v += bias[n];
            if (accum) v += C[(long)m * ldc + n];
            if (act) v = fmaxf(v, 0.f);
            C[(long)m * ldc + n] = v;
        }
    }
}

__global__ __launch_bounds__(256) void copy_f(const float* __restrict__ x, float* __restrict__ y, int n) {
    int i = blockIdx.x * 256 + threadIdx.x;
    if (i < n) y[i] = x[i];
}
__global__ __launch_bounds__(256) void zero_f(float* __restrict__ x, int n) {
    int i = blockIdx.x * 256 + threadIdx.x;
    if (i < n) x[i] = 0.f;
}

// rcv_ie[n, 0:256] = sum_{r: subj(r)=n} m_ip[r,:], rcv_ie[n, 256:512] = same for obj.
// One block per entity node n; pairs staged in LDS; r-ascending accumulation.
// Block-uniform compares -> scalar branches, loads only on match.
__global__ __launch_bounds__(256)
void edge_scatter_sum(const float* __restrict__ m_ip, const int* __restrict__ pair,
                      float* __restrict__ rcv_ie, int R) {
    __shared__ int sp[8192];
    const int n = blockIdx.x;
    const int c = threadIdx.x;
    for (int i = threadIdx.x; i < 2 * R; i += 256) sp[i] = pair[i];
    __syncthreads();
    float as = 0.f, ao = 0.f;
    for (int r = 0; r < R; ++r) {
        int s = sp[2 * r], o = sp[2 * r + 1];
        if (s == n) as += m_ip[(long)r * 256 + c];
        if (o == n) ao += m_ip[(long)r * 256 + c];
    }
    rcv_ie[(long)n * 768 + c]       = as;
    rcv_ie[(long)n * 768 + 256 + c] = ao;
}

// Row softmax, cols <= 256, one 256-thread block (4 waves) per row.
__global__ __launch_bounds__(256)
void softmax_rows(const float* __restrict__ X, float* __restrict__ Y, int cols) {
    const int r = blockIdx.x;
    const int t = threadIdx.x;
    __shared__ float sm[4];
    float v = (t < cols) ? X[(long)r * cols + t] : -1e30f;
    float m = v;
    #pragma unroll
    for (int o = 32; o > 0; o >>= 1) m = fmaxf(m, __shfl_down(m, o));
    if ((t & 63) == 0) sm[t >> 6] = m;
    __syncthreads();
    float m0 = fmaxf(fmaxf(sm[0], sm[1]), fmaxf(sm[2], sm[3]));
    float e = (t < cols) ? expf(v - m0) : 0.f;
    float s = e;
    #pragma unroll
    for (int o = 32; o > 0; o >>= 1) s += __shfl_down(s, o);
    __syncthreads();
    if ((t & 63) == 0) sm[t >> 6] = s;
    __syncthreads();
    float s0 = sm[0] + sm[1] + sm[2] + sm[3];
    if (t < cols) Y[(long)r * cols + t] = e / s0;
}

// rcv_ip[:,0:256] = m_ie[subj], rcv_ip[:,256:512] = m_ie[obj]  (gather, deterministic)
__global__ __launch_bounds__(256)
void gather_msgs(const float* __restrict__ m_ie, const int* __restrict__ pair,
                 float* __restrict__ rcv_ip, int R) {
    int i = blockIdx.x * 256 + threadIdx.x;
    if (i >= R * 256) return;
    int r = i >> 8, c = i & 255;
    int s = pair[2 * r], o = pair[2 * r + 1];
    rcv_ip[(long)r * 768 + c]       = m_ie[(long)s * 256 + c];
    rcv_ip[(long)r * 768 + 256 + c] = m_ie[(long)o * 256 + c];
}

// gbuf layout [n, 3*1024]: cols 0:1024 = gz pre-act, 1024:2048 = gr, 2048:3072 = gh partial
__global__ __launch_bounds__(256)
void gru_ew1(const float* __restrict__ gbuf, const float* __restrict__ bW, const float* __restrict__ bU,
             const float* __restrict__ node, float* __restrict__ zbuf, float* __restrict__ rbuf, int total) {
    int i = blockIdx.x * 256 + threadIdx.x;
    if (i >= total) return;
    int col = i & 1023;
    int row = i >> 10;
    const float* g = gbuf + (long)row * 3072;
    float gz = g[col]        + bW[col]        + bU[col];
    float gr = g[1024 + col] + bW[1024 + col] + bU[1024 + col];
    float z = 1.f / (1.f + expf(-gz));
    float r = 1.f / (1.f + expf(-gr));
    zbuf[i] = z;
    rbuf[i] = r * node[i];
}
__global__ __launch_bounds__(256)
void gru_ew2(const float* __restrict__ gbuf, const float* __restrict__ bW, const float* __restrict__ bU,
             float* __restrict__ node, const float* __restrict__ zbuf, int total) {
    int i = blockIdx.x * 256 + threadIdx.x;
    if (i >= total) return;
    int col = i & 1023;
    int row = i >> 10;
    float gh = gbuf[(long)row * 3072 + 2048 + col] + bW[2048 + col] + bU[2048 + col];
    float h = tanhf(gh);
    float z = zbuf[i];
    node[i] = (1.f - z) * node[i] + z * h;
}

extern "C" void kernel_launch(void* const* d_in, const int* in_sizes, int n_in,
                              void* d_out, int out_size, void* d_ws, size_t ws_size,
                              hipStream_t stream)
{
    constexpr int D = 1024, D2 = 512, D4 = 256, K3 = 3;
    constexpr int CE = 151, CR = 51, EMB = 300, NN = 512, RR = 4096;
    constexpr int MO = 1792, MI = 768, T = 3;
    (void)in_sizes; (void)n_in; (void)out_size;

    const float* roi      = (const float*)d_in[0];
    const float* uni      = (const float*)d_in[1];
    const int*   pair     = (const int*)  d_in[2];
    const float* obj_log  = (const float*)d_in[3];
    const float* emb_ent  = (const float*)d_in[4];
    const float* emb_prd  = (const float*)d_in[5];
    const float* adj_e2e  = (const float*)d_in[6];
    const float* adj_e2p  = (const float*)d_in[7];
    const float* adj_p2e  = (const float*)d_in[8];
    const float* adj_p2p  = (const float*)d_in[9];
    const float* init_ew  = (const float*)d_in[10];
    const float* init_eb  = (const float*)d_in[11];
    const float* init_pw  = (const float*)d_in[12];
    const float* init_pb  = (const float*)d_in[13];
    const float* send_w1  = (const float*)d_in[14];
    const float* send_b1  = (const float*)d_in[15];
    const float* send_w2  = (const float*)d_in[16];
    const float* send_b2  = (const float*)d_in[17];
    const float* r_oe_w1  = (const float*)d_in[18];
    const float* r_oe_b1  = (const float*)d_in[19];
    const float* r_oe_w2  = (const float*)d_in[20];
    const float* r_oe_b2  = (const float*)d_in[21];
    const float* r_op_w1  = (const float*)d_in[22];
    const float* r_op_b1  = (const float*)d_in[23];
    const float* r_op_w2  = (const float*)d_in[24];
    const float* r_op_b2  = (const float*)d_in[25];
    const float* r_ie_w1  = (const float*)d_in[26];
    const float* r_ie_b1  = (const float*)d_in[27];
    const float* r_ie_w2  = (const float*)d_in[28];
    const float* r_ie_b2  = (const float*)d_in[29];
    const float* r_ip_w1  = (const float*)d_in[30];
    const float* r_ip_b1  = (const float*)d_in[31];
    const float* r_ip_w2  = (const float*)d_in[32];
    const float* r_ip_b2  = (const float*)d_in[33];
    const float* gru_W    = (const float*)d_in[34];
    const float* gru_U    = (const float*)d_in[35];
    const float* gru_bW   = (const float*)d_in[36];
    const float* gru_bU   = (const float*)d_in[37];
    const float* out_w1   = (const float*)d_in[38];
    const float* out_b1   = (const float*)d_in[39];
    const float* out_w2   = (const float*)d_in[40];
    const float* out_b2   = (const float*)d_in[41];

    // Final logits live directly in d_out (fully rewritten every iteration).
    float* entlg = (float*)d_out;                    // [512, 151]
    float* prdlg = (float*)d_out + (long)NN * CE;    // [4096, 51]

    // ---- workspace bump allocator (fp32) ----
    float* p = (float*)d_ws;
    auto alloc = [&](long n) { float* q = p; p += n; return q; };
    float* oe    = alloc((long)CE * D);
    float* op    = alloc((long)CR * D);
    float* ie    = alloc((long)NN * D);
    float* ipn   = alloc((long)RR * D);
    float* E_ent = alloc((long)NN * CE);
    float* E_prd = alloc((long)RR * CR);
    float* m_oe  = alloc((long)CE * D4);
    float* m_op  = alloc((long)CR * D4);
    float* m_ie  = alloc((long)NN * D4);
    float* m_ip  = alloc((long)RR * D4);
    float* rc_oe = alloc((long)CE * MO);
    float* rc_op = alloc((long)CR * MO);
    float* rc_ie = alloc((long)NN * MI);
    float* rc_ip = alloc((long)RR * MI);
    float* hid   = alloc((long)RR * D);       // shared hidden buffer (max 4096x1024)
    float* msg   = alloc((long)RR * D);       // recv MLP output / GRU msg input
    float* gbuf  = alloc((long)RR * 3 * D);   // GRU gate pre-activations
    float* zbuf  = alloc((long)RR * D);
    float* rbuf  = alloc((long)RR * D);
    float* f_a   = alloc((long)RR * D);
    float* f_b   = alloc((long)CE * D);
    size_t need = (size_t)(p - (float*)d_ws) * sizeof(float);  // ~176 MB
    if (ws_size < need) return;  // insufficient scratch: output stays poison (fails loudly)

    auto grid1 = [](long n) { return dim3((unsigned)((n + 255) / 256)); };

    // Batched GEMM launcher: 128x128/8x8 kernel when the dispatch is big enough
    // to feed ~half the CUs; otherwise 64x64/4x4. Aligned (checkless) variants
    // when every tile edge is full. Accumulation order identical across all.
    auto gemm_b = [&](const float* A, int lda, int tA, long sA,
                      const float* B, int ldb, int tB, long sB,
                      const float* bias, float* C, int ldc, long sC,
                      int M, int Nn, int Kk, int act, int accum, int nz) {
        long bx = (Nn + 127) / 128, by = (M + 127) / 128;
        if (M >= 1024 && Nn >= 128 && bx * by * nz >= 128) {
            dim3 g((unsigned)bx, (unsigned)by, nz);
            bool al = (M % 128 == 0) && (Nn % 128 == 0) && (Kk % 16 == 0);
            if (al) gemm_kernel128<true><<<g, 256, 0, stream>>>(A, lda, tA, sA, B, ldb, tB, sB,
                                                                bias, C, ldc, sC, M, Nn, Kk, act, accum);
            else    gemm_kernel128<false><<<g, 256, 0, stream>>>(A, lda, tA, sA, B, ldb, tB, sB,
                                                                 bias, C, ldc, sC, M, Nn, Kk, act, accum);
        } else {
            dim3 g((Nn + 63) / 64, (M + 63) / 64, nz);
            bool al = (M % 64 == 0) && (Nn % 64 == 0) && (Kk % 16 == 0);
            if (al) gemm_kernel64<true><<<g, 256, 0, stream>>>(A, lda, tA, sA, B, ldb, tB, sB,
                                                               bias, C, ldc, sC, M, Nn, Kk, act, accum);
            else    gemm_kernel64<false><<<g, 256, 0, stream>>>(A, lda, tA, sA, B, ldb, tB, sB,
                                                                bias, C, ldc, sC, M, Nn, Kk, act, accum);
        }
    };
    auto gemm = [&](const float* A, int lda, int tA, const float* B, int ldb, const float* bias,
                    float* C, int ldc, int M, int Nn, int Kk, int act, int accum) {
        gemm_b(A, lda, tA, 0, B, ldb, 0, 0, bias, C, ldc, 0, M, Nn, Kk, act, accum, 1);
    };

    // ---- init ----
    copy_f<<<grid1((long)NN * D), 256, 0, stream>>>(roi, ie, NN * D);
    copy_f<<<grid1((long)RR * D), 256, 0, stream>>>(uni, ipn, RR * D);
    gemm(emb_ent, EMB, 0, init_ew, D, init_eb, oe, D, CE, D, EMB, 0, 0);
    gemm(emb_prd, EMB, 0, init_pw, D, init_pb, op, D, CR, D, EMB, 0, 0);
    copy_f<<<grid1((long)NN * CE), 256, 0, stream>>>(obj_log, entlg, NN * CE);
    softmax_rows<<<NN, 256, 0, stream>>>(entlg, E_ent, CE);
    zero_f<<<grid1((long)RR * CR), 256, 0, stream>>>(E_prd, RR * CR);

    for (int t = 0; t < T; ++t) {
        // ---- send MLPs (relu both layers) ----
        auto send = [&](const float* X, int n, int idx, float* out) {
            gemm(X, D, 0, send_w1 + (long)idx * D * D2, D2, send_b1 + idx * D2, hid, D2, n, D2, D, 1, 0);
            gemm(hid, D2, 0, send_w2 + (long)idx * D2 * D4, D4, send_b2 + idx * D4, out, D4, n, D4, D2, 1, 0);
        };
        send(oe, CE, 0, m_oe);
        send(op, CR, 1, m_op);
        send(ie, NN, 2, m_ie);
        send(ipn, RR, 3, m_ip);

        // ---- receive (adjacency einsums batched over k via grid.z) ----
        // rcv_oe = [e2e(3x256) | p2e(3x256) | E_ent^T m_ie]
        gemm_b(adj_e2e, CE, 1, (long)CE * CE, m_oe, D4, 0, 0, nullptr,
               rc_oe, MO, D4, CE, D4, CE, 0, 0, K3);
        gemm_b(adj_p2e, CE, 1, (long)CR * CE, m_op, D4, 0, 0, nullptr,
               rc_oe + 3 * D4, MO, D4, CE, D4, CR, 0, 0, K3);
        gemm(E_ent, CE, 1, m_ie, D4, nullptr, rc_oe + 6 * D4, MO, CE, D4, NN, 0, 0);
        // rcv_op = [e2p | p2p | E_pred^T m_ip]
        gemm_b(adj_e2p, CR, 1, (long)CE * CR, m_oe, D4, 0, 0, nullptr,
               rc_op, MO, D4, CR, D4, CE, 0, 0, K3);
        gemm_b(adj_p2p, CR, 1, (long)CR * CR, m_op, D4, 0, 0, nullptr,
               rc_op + 3 * D4, MO, D4, CR, D4, CR, 0, 0, K3);
        gemm(E_prd, CR, 1, m_ip, D4, nullptr, rc_op + 6 * D4, MO, CR, D4, RR, 0, 0);
        // rcv_ie = [edge-scan subj | edge-scan obj | E_ent @ m_oe]  (deterministic)
        edge_scatter_sum<<<NN, 256, 0, stream>>>(m_ip, pair, rc_ie, RR);
        gemm(E_ent, CE, 0, m_oe, D4, nullptr, rc_ie + 2 * D4, MI, NN, D4, CE, 0, 0);
        // rcv_ip = [gather subj | gather obj | E_pred @ m_op]
        gather_msgs<<<grid1((long)RR * D4), 256, 0, stream>>>(m_ie, pair, rc_ip, RR);
        gemm(E_prd, CR, 0, m_op, D4, nullptr, rc_ip + 2 * D4, MI, RR, D4, CR, 0, 0);

        // ---- recv MLP + GRU per node type (gate GEMMs batched via grid.z) ----
        auto gru = [&](float* X, int n, int tix) {
            const float* W  = gru_W  + (long)tix * 3 * D * D;
            const float* U  = gru_U  + (long)tix * 3 * D * D;
            const float* bW = gru_bW + (long)tix * 3 * D;
            const float* bU = gru_bU + (long)tix * 3 * D;
            // gbuf[:, g*D:(g+1)*D] = msg @ W[g], g = 0,1,2 (one batched launch)
            gemm_b(msg, D, 0, 0, W, D, 0, (long)D * D, nullptr,
                   gbuf, 3 * D, D, n, D, D, 0, 0, 3);
            // gbuf[:, g*D:(g+1)*D] += X @ U[g], g = 0,1 (z and r gates)
            gemm_b(X, D, 0, 0, U, D, 0, (long)D * D, nullptr,
                   gbuf, 3 * D, D, n, D, D, 0, 1, 2);
            gru_ew1<<<grid1((long)n * D), 256, 0, stream>>>(gbuf, bW, bU, X, zbuf, rbuf, n * D);
            gemm(rbuf, D, 0, U + (long)2 * D * D, D, nullptr, gbuf + 2 * D, 3 * D, n, D, D, 0, 1);
            gru_ew2<<<grid1((long)n * D), 256, 0, stream>>>(gbuf, bW, bU, X, zbuf, n * D);
        };
        auto recv_gru = [&](const float* rcv, int n, int m_in, const float* w1, const float* b1,
                            const float* w2, const float* b2, float* X, int tix) {
            gemm(rcv, m_in, 0, w1, m_in, b1, hid, m_in, n, m_in, m_in, 1, 0);
            gemm(hid, m_in, 0, w2, D, b2, msg, D, n, D, m_in, 1, 0);
            gru(X, n, tix);
        };
        recv_gru(rc_oe, CE, MO, r_oe_w1, r_oe_b1, r_oe_w2, r_oe_b2, oe, 0);
        recv_gru(rc_op, CR, MO, r_op_w1, r_op_b1, r_op_w2, r_op_b2, op, 1);
        recv_gru(rc_ie, NN, MI, r_ie_w1, r_ie_b1, r_ie_w2, r_ie_b2, ie, 2);
        recv_gru(rc_ip, RR, MI, r_ip_w1, r_ip_b1, r_ip_w2, r_ip_b2, ipn, 3);

        // ---- output projections + logits (fused transB) + softmax bridges ----
        auto outmlp = [&](const float* X, int n, int idx, float* out) {
            gemm(X, D, 0, out_w1 + (long)idx * D * D, D, out_b1 + idx * D, hid, D, n, D, D, 1, 0);
            gemm(hid, D, 0, out_w2 + (long)idx * D * D, D, out_b2 + idx * D, out, D, n, D, D, 0, 0);
        };
        outmlp(ie, NN, 0, f_a);
        outmlp(oe, CE, 1, f_b);
        gemm_b(f_a, D, 0, 0, f_b, D, 1, 0, nullptr, entlg, CE, 0, NN, CE, D, 0, 0, 1);
        outmlp(ipn, RR, 2, f_a);
        outmlp(op, CR, 3, f_b);
        gemm_b(f_a, D, 0, 0, f_b, D, 1, 0, nullptr, prdlg, CR, 0, RR, CR, D, 0, 0, 1);
        softmax_rows<<<NN, 256, 0, stream>>>(entlg, E_ent, CE);
        softmax_rows<<<RR, 256, 0, stream>>>(prdlg, E_prd, CR);
    }
    // outputs already in d_out: ent_logits [512,151] then pred_logits [4096,51], fp32
}

// Round 8
// 12642.237 us; speedup vs baseline: 5.3062x; 5.3062x over previous
//
#include <hip/hip_runtime.h>

// ---------------------------------------------------------------------------
// Plain tiled batched GEMM (round-4 proven config, plain launch_bounds(256)):
//   C_z[M,N] = act( op(A_z)(MxK) @ op(B_z)(KxN) + bias + (accum ? C_z : 0) )
// BM x 64 C-tile, 256 threads, (BM/16)x4 register tile, K-tile 16,
// double-buffered LDS with register staging. Deterministic: per-output
// accumulation is single-thread, t-ascending, kk-ascending (identical across
// BM=64 / BM=128 / grouped kernels -> bitwise-stable results).
// ---------------------------------------------------------------------------
template<int BM>
__global__ __launch_bounds__(256)
void gemm_kernel(const float* __restrict__ A, int lda, int transA, long sA,
                 const float* __restrict__ B, int ldb, int transB, long sB,
                 const float* __restrict__ bias,
                 float* __restrict__ C, int ldc, long sC,
                 int M, int N, int K, int act, int accum)
{
    constexpr int TM = BM / 16;
    constexpr int AF4 = BM / 64;
    constexpr int LDS_A = BM + 4;
    __shared__ __align__(16) float As[2][16][LDS_A];
    __shared__ __align__(16) float Bs[2][16][68];
    {
        const long z = blockIdx.z;
        A += z * sA; B += z * sB; C += z * sC;
    }
    const int tid = threadIdx.x;
    const int bm = blockIdx.y * BM;
    const int bn = blockIdx.x * 64;
    const int tr = tid >> 4, tc = tid & 15;
    float acc[TM][4] = {};
    const int nt = (K + 15) / 16;
    float4 ra[AF4]; float4 rb;

    auto g_load = [&](int t) {
        const int k0 = t * 16;
        if (!transA) {
            #pragma unroll
            for (int j = 0; j < AF4; ++j) {
                int idx = tid + j * 256;
                int m = idx >> 2, kc = (idx & 3) * 4;
                float4 v = {0.f, 0.f, 0.f, 0.f};
                if (bm + m < M) {
                    const float* ap = A + (long)(bm + m) * lda + k0 + kc;
                    if (k0 + kc + 3 < K) v = *(const float4*)ap;
                    else { float t4[4] = {0.f,0.f,0.f,0.f};
                           for (int q = 0; q < 4; ++q) if (k0 + kc + q < K) t4[q] = ap[q];
                           v = *(float4*)t4; }
                }
                ra[j] = v;
            }
        } else {
            #pragma unroll
            for (int j = 0; j < AF4; ++j) {
                int idx = tid + j * 256;
                int kk = idx / (BM / 4), mc = (idx % (BM / 4)) * 4;
                float4 v = {0.f, 0.f, 0.f, 0.f};
                if (k0 + kk < K) {
                    const float* ap = A + (long)(k0 + kk) * lda + bm + mc;
                    if (bm + mc + 3 < M) v = *(const float4*)ap;
                    else { float t4[4] = {0.f,0.f,0.f,0.f};
                           for (int q = 0; q < 4; ++q) if (bm + mc + q < M) t4[q] = ap[q];
                           v = *(float4*)t4; }
                }
                ra[j] = v;
            }
        }
        if (!transB) {
            int kk = tid >> 4, nc = (tid & 15) * 4;
            float4 v = {0.f, 0.f, 0.f, 0.f};
            if (k0 + kk < K) {
                const float* bp = B + (long)(k0 + kk) * ldb + bn + nc;
                if (bn + nc + 3 < N) v = *(const float4*)bp;
                else { float t4[4] = {0.f,0.f,0.f,0.f};
                       for (int q = 0; q < 4; ++q) if (bn + nc + q < N) t4[q] = bp[q];
                       v = *(float4*)t4; }
            }
            rb = v;
        } else {
            int n = tid >> 2, kc = (tid & 3) * 4;
            float4 v = {0.f, 0.f, 0.f, 0.f};
            if (bn + n < N) {
                const float* bp = B + (long)(bn + n) * ldb + k0 + kc;
                if (k0 + kc + 3 < K) v = *(const float4*)bp;
                else { float t4[4] = {0.f,0.f,0.f,0.f};
                       for (int q = 0; q < 4; ++q) if (k0 + kc + q < K) t4[q] = bp[q];
                       v = *(float4*)t4; }
            }
            rb = v;
        }
    };
    auto s_store = [&](int buf) {
        if (!transA) {
            #pragma unroll
            for (int j = 0; j < AF4; ++j) {
                int idx = tid + j * 256;
                int m = idx >> 2, kc = (idx & 3) * 4;
                As[buf][kc + 0][m] = ra[j].x; As[buf][kc + 1][m] = ra[j].y;
                As[buf][kc + 2][m] = ra[j].z; As[buf][kc + 3][m] = ra[j].w;
            }
        } else {
            #pragma unroll
            for (int j = 0; j < AF4; ++j) {
                int idx = tid + j * 256;
                int kk = idx / (BM / 4), mc = (idx % (BM / 4)) * 4;
                *(float4*)&As[buf][kk][mc] = ra[j];
            }
        }
        if (!transB) {
            int kk = tid >> 4, nc = (tid & 15) * 4;
            *(float4*)&Bs[buf][kk][nc] = rb;
        } else {
            int n = tid >> 2, kc = (tid & 3) * 4;
            Bs[buf][kc + 0][n] = rb.x; Bs[buf][kc + 1][n] = rb.y;
            Bs[buf][kc + 2][n] = rb.z; Bs[buf][kc + 3][n] = rb.w;
        }
    };

    g_load(0); s_store(0);
    __syncthreads();
    for (int t = 0; t < nt; ++t) {
        const int cur = t & 1;
        if (t + 1 < nt) g_load(t + 1);
        #pragma unroll
        for (int kk = 0; kk < 16; ++kk) {
            const float4 b4 = *(const float4*)&Bs[cur][kk][tc * 4];
            const float bb[4] = {b4.x, b4.y, b4.z, b4.w};
            #pragma unroll
            for (int j = 0; j < AF4; ++j) {
                const float4 a4 = *(const float4*)&As[cur][kk][tr * TM + j * 4];
                const float aa[4] = {a4.x, a4.y, a4.z, a4.w};
                #pragma unroll
                for (int im = 0; im < 4; ++im)
                    #pragma unroll
                    for (int in = 0; in < 4; ++in)
                        acc[j * 4 + im][in] += aa[im] * bb[in];
            }
        }
        if (t + 1 < nt) s_store(cur ^ 1);
        __syncthreads();
    }
    #pragma unroll
    for (int j = 0; j < AF4; ++j) {
        #pragma unroll
        for (int im = 0; im < 4; ++im) {
            int m = bm + tr * TM + j * 4 + im;
            if (m >= M) continue;
            #pragma unroll
            for (int in = 0; in < 4; ++in) {
                int n = bn + tc * 4 + in;
                if (n >= N) continue;
                float v = acc[j * 4 + im][in];
                if (bias) v += bias[n];
                if (accum) v += C[(long)m * ldc + n];
                if (act) v = fmaxf(v, 0.f);
                C[(long)m * ldc + n] = v;
            }
        }
    }
}

// ---------------------------------------------------------------------------
// GROUPED GEMM: up to 4 groups share one dispatch. blockIdx.y -> row tile of
// group g (via tOff prefix); per-group A,B,C,bias,M,K,lda,ldb,ldc; blockIdx.z
// batches gates (A += z*sAz[g], B += z*sBz, C += z*zColC). Tile/compute body
// is byte-identical to gemm_kernel<128> (no transB needed) -> bitwise-same
// accumulation. Plain launch_bounds(256): NO min-waves arg (round-6 lesson:
// it forces VGPR caps that spill the accumulator -> 16 GB scratch traffic).
// ---------------------------------------------------------------------------
struct GG {
    const float* A[4]; const float* B[4]; float* C[4]; const float* bias[4];
    long sAz[4];
    int M[4], K[4], lda[4], ldb[4], ldc[4];
    int tOff[5];
    long sBz, zColC;
    int transA, act, accum;
};

__global__ __launch_bounds__(256)
void gemm_grouped(GG p, int N)
{
    __shared__ __align__(16) float As[2][16][132];
    __shared__ __align__(16) float Bs[2][16][68];
    const int by = blockIdx.y;
    const int g = (by >= p.tOff[1]) + (by >= p.tOff[2]) + (by >= p.tOff[3]);
    const int bm = (by - p.tOff[g]) * 128;
    const int bn = blockIdx.x * 64;
    const long z = blockIdx.z;
    const float* __restrict__ A = p.A[g] + z * p.sAz[g];
    const float* __restrict__ B = p.B[g] + z * p.sBz;
    float* __restrict__ C = p.C[g] + z * p.zColC;
    const float* __restrict__ bias = p.bias[g];
    const int M = p.M[g], K = p.K[g];
    const int lda = p.lda[g], ldb = p.ldb[g], ldc = p.ldc[g];
    const int transA = p.transA;
    const int act = p.act, accum = p.accum;
    const int tid = threadIdx.x;
    const int tr = tid >> 4, tc = tid & 15;
    float acc[8][4] = {};
    const int nt = (K + 15) / 16;
    float4 ra[2]; float4 rb;

    auto g_load = [&](int t) {
        const int k0 = t * 16;
        if (!transA) {
            #pragma unroll
            for (int j = 0; j < 2; ++j) {
                int idx = tid + j * 256;
                int m = idx >> 2, kc = (idx & 3) * 4;
                float4 v = {0.f, 0.f, 0.f, 0.f};
                if (bm + m < M) {
                    const float* ap = A + (long)(bm + m) * lda + k0 + kc;
                    if (k0 + kc + 3 < K) v = *(const float4*)ap;
                    else { float t4[4] = {0.f,0.f,0.f,0.f};
                           for (int q = 0; q < 4; ++q) if (k0 + kc + q < K) t4[q] = ap[q];
                           v = *(float4*)t4; }
                }
                ra[j] = v;
            }
        } else {
            #pragma unroll
            for (int j = 0; j < 2; ++j) {
                int idx = tid + j * 256;
                int kk = idx >> 5, mc = (idx & 31) * 4;
                float4 v = {0.f, 0.f, 0.f, 0.f};
                if (k0 + kk < K) {
                    const float* ap = A + (long)(k0 + kk) * lda + bm + mc;
                    if (bm + mc + 3 < M) v = *(const float4*)ap;
                    else { float t4[4] = {0.f,0.f,0.f,0.f};
                           for (int q = 0; q < 4; ++q) if (bm + mc + q < M) t4[q] = ap[q];
                           v = *(float4*)t4; }
                }
                ra[j] = v;
            }
        }
        {
            int kk = tid >> 4, nc = (tid & 15) * 4;
            float4 v = {0.f, 0.f, 0.f, 0.f};
            if (k0 + kk < K) {
                const float* bp = B + (long)(k0 + kk) * ldb + bn + nc;
                if (bn + nc + 3 < N) v = *(const float4*)bp;
                else { float t4[4] = {0.f,0.f,0.f,0.f};
                       for (int q = 0; q < 4; ++q) if (bn + nc + q < N) t4[q] = bp[q];
                       v = *(float4*)t4; }
            }
            rb = v;
        }
    };
    auto s_store = [&](int buf) {
        if (!transA) {
            #pragma unroll
            for (int j = 0; j < 2; ++j) {
                int idx = tid + j * 256;
                int m = idx >> 2, kc = (idx & 3) * 4;
                As[buf][kc + 0][m] = ra[j].x; As[buf][kc + 1][m] = ra[j].y;
                As[buf][kc + 2][m] = ra[j].z; As[buf][kc + 3][m] = ra[j].w;
            }
        } else {
            #pragma unroll
            for (int j = 0; j < 2; ++j) {
                int idx = tid + j * 256;
                int kk = idx >> 5, mc = (idx & 31) * 4;
                *(float4*)&As[buf][kk][mc] = ra[j];
            }
        }
        {
            int kk = tid >> 4, nc = (tid & 15) * 4;
            *(float4*)&Bs[buf][kk][nc] = rb;
        }
    };

    g_load(0); s_store(0);
    __syncthreads();
    for (int t = 0; t < nt; ++t) {
        const int cur = t & 1;
        if (t + 1 < nt) g_load(t + 1);
        #pragma unroll
        for (int kk = 0; kk < 16; ++kk) {
            const float4 b4 = *(const float4*)&Bs[cur][kk][tc * 4];
            const float bb[4] = {b4.x, b4.y, b4.z, b4.w};
            #pragma unroll
            for (int j = 0; j < 2; ++j) {
                const float4 a4 = *(const float4*)&As[cur][kk][tr * 8 + j * 4];
                const float aa[4] = {a4.x, a4.y, a4.z, a4.w};
                #pragma unroll
                for (int im = 0; im < 4; ++im)
                    #pragma unroll
                    for (int in = 0; in < 4; ++in)
                        acc[j * 4 + im][in] += aa[im] * bb[in];
            }
        }
        if (t + 1 < nt) s_store(cur ^ 1);
        __syncthreads();
    }
    #pragma unroll
    for (int j = 0; j < 2; ++j) {
        #pragma unroll
        for (int im = 0; im < 4; ++im) {
            int m = bm + tr * 8 + j * 4 + im;
            if (m >= M) continue;
            #pragma unroll
            for (int in = 0; in < 4; ++in) {
                int n = bn + tc * 4 + in;
                if (n >= N) continue;
                float v = acc[j * 4 + im][in];
                if (bias) v += bias[n];
                if (accum) v += C[(long)m * ldc + n];
                if (act) v = fmaxf(v, 0.f);
                C[(long)m * ldc + n] = v;
            }
        }
    }
}

__global__ __launch_bounds__(256) void copy_f(const float* __restrict__ x, float* __restrict__ y, int n) {
    int i = blockIdx.x * 256 + threadIdx.x;
    if (i < n) y[i] = x[i];
}
__global__ __launch_bounds__(256) void zero_f(float* __restrict__ x, int n) {
    int i = blockIdx.x * 256 + threadIdx.x;
    if (i < n) x[i] = 0.f;
}

// rcv_ie[n, 0:256] = sum_{r: subj(r)=n} m_ip[r,:]; cols 256:512 same for obj.
// One block per entity node; pairs staged in LDS; r-ascending accumulation.
__global__ __launch_bounds__(256)
void edge_scatter_sum(const float* __restrict__ m_ip, const int* __restrict__ pair,
                      float* __restrict__ rcv_ie, int R) {
    __shared__ int sp[8192];
    const int n = blockIdx.x;
    const int c = threadIdx.x;
    for (int i = threadIdx.x; i < 2 * R; i += 256) sp[i] = pair[i];
    __syncthreads();
    float as = 0.f, ao = 0.f;
    for (int r = 0; r < R; ++r) {
        int s = sp[2 * r], o = sp[2 * r + 1];
        if (s == n) as += m_ip[(long)r * 256 + c];
        if (o == n) ao += m_ip[(long)r * 256 + c];
    }
    rcv_ie[(long)n * 768 + c]       = as;
    rcv_ie[(long)n * 768 + 256 + c] = ao;
}

// Row softmax, cols <= 256, one 256-thread block per row.
__global__ __launch_bounds__(256)
void softmax_rows(const float* __restrict__ X, float* __restrict__ Y, int cols) {
    const int r = blockIdx.x;
    const int t = threadIdx.x;
    __shared__ float sm[4];
    float v = (t < cols) ? X[(long)r * cols + t] : -1e30f;
    float m = v;
    #pragma unroll
    for (int o = 32; o > 0; o >>= 1) m = fmaxf(m, __shfl_down(m, o));
    if ((t & 63) == 0) sm[t >> 6] = m;
    __syncthreads();
    float m0 = fmaxf(fmaxf(sm[0], sm[1]), fmaxf(sm[2], sm[3]));
    float e = (t < cols) ? expf(v - m0) : 0.f;
    float s = e;
    #pragma unroll
    for (int o = 32; o > 0; o >>= 1) s += __shfl_down(s, o);
    __syncthreads();
    if ((t & 63) == 0) sm[t >> 6] = s;
    __syncthreads();
    float s0 = sm[0] + sm[1] + sm[2] + sm[3];
    if (t < cols) Y[(long)r * cols + t] = e / s0;
}

// rcv_ip[:,0:256] = m_ie[subj], rcv_ip[:,256:512] = m_ie[obj]
__global__ __launch_bounds__(256)
void gather_msgs(const float* __restrict__ m_ie, const int* __restrict__ pair,
                 float* __restrict__ rcv_ip, int R) {
    int i = blockIdx.x * 256 + threadIdx.x;
    if (i >= R * 256) return;
    int r = i >> 8, c = i & 255;
    int s = pair[2 * r], o = pair[2 * r + 1];
    rcv_ip[(long)r * 768 + c]       = m_ie[(long)s * 256 + c];
    rcv_ip[(long)r * 768 + 256 + c] = m_ie[(long)o * 256 + c];
}

// Grouped GRU elementwise over concatenated rows [oe|op|ie|ip] = 4810 rows.
// Row->type boundaries {151,202,714}; math identical to prior gru_ew1/ew2.
__global__ __launch_bounds__(256)
void gru_ew1_g(const float* __restrict__ gbuf, const float* __restrict__ bW, const float* __restrict__ bU,
               const float* __restrict__ X0, const float* __restrict__ X1,
               const float* __restrict__ X2, const float* __restrict__ X3,
               float* __restrict__ zbuf, float* __restrict__ rbuf, int total) {
    int i = blockIdx.x * 256 + threadIdx.x;
    if (i >= total) return;
    int row = i >> 10, col = i & 1023;
    int g = (row >= 151) + (row >= 202) + (row >= 714);
    int off = (g == 0) ? 0 : (g == 1) ? 151 : (g == 2) ? 202 : 714;
    const float* X = (g == 0) ? X0 : (g == 1) ? X1 : (g == 2) ? X2 : X3;
    const float* gb = gbuf + (long)row * 3072;
    const float* bWg = bW + g * 3072;
    const float* bUg = bU + g * 3072;
    float gz = gb[col]        + bWg[col]        + bUg[col];
    float gr = gb[1024 + col] + bWg[1024 + col] + bUg[1024 + col];
    float zz = 1.f / (1.f + expf(-gz));
    float rr = 1.f / (1.f + expf(-gr));
    zbuf[i] = zz;
    rbuf[i] = rr * X[(long)(row - off) * 1024 + col];
}
__global__ __launch_bounds__(256)
void gru_ew2_g(const float* __restrict__ gbuf, const float* __restrict__ bW, const float* __restrict__ bU,
               float* __restrict__ X0, float* __restrict__ X1,
               float* __restrict__ X2, float* __restrict__ X3,
               const float* __restrict__ zbuf, int total) {
    int i = blockIdx.x * 256 + threadIdx.x;
    if (i >= total) return;
    int row = i >> 10, col = i & 1023;
    int g = (row >= 151) + (row >= 202) + (row >= 714);
    int off = (g == 0) ? 0 : (g == 1) ? 151 : (g == 2) ? 202 : 714;
    float* X = (g == 0) ? X0 : (g == 1) ? X1 : (g == 2) ? X2 : X3;
    float gh = gbuf[(long)row * 3072 + 2048 + col] + bW[g * 3072 + 2048 + col] + bU[g * 3072 + 2048 + col];
    float h = tanhf(gh);
    float zz = zbuf[i];
    long xi = (long)(row - off) * 1024 + col;
    X[xi] = (1.f - zz) * X[xi] + zz * h;
}

extern "C" void kernel_launch(void* const* d_in, const int* in_sizes, int n_in,
                              void* d_out, int out_size, void* d_ws, size_t ws_size,
                              hipStream_t stream)
{
    constexpr int D = 1024, D2 = 512, D4 = 256, K3 = 3;
    constexpr int CE = 151, CR = 51, EMB = 300, NN = 512, RR = 4096;
    constexpr int MO = 1792, MI = 768, T = 3;
    constexpr int NT = CE + CR + NN + RR;  // 4810 concatenated rows [oe|op|ie|ip]
    constexpr int OF_OE = 0, OF_OP = CE, OF_IE = CE + CR, OF_IP = CE + CR + NN;
    (void)in_sizes; (void)n_in; (void)out_size;

    const float* roi      = (const float*)d_in[0];
    const float* uni      = (const float*)d_in[1];
    const int*   pair     = (const int*)  d_in[2];
    const float* obj_log  = (const float*)d_in[3];
    const float* emb_ent  = (const float*)d_in[4];
    const float* emb_prd  = (const float*)d_in[5];
    const float* adj_e2e  = (const float*)d_in[6];
    const float* adj_e2p  = (const float*)d_in[7];
    const float* adj_p2e  = (const float*)d_in[8];
    const float* adj_p2p  = (const float*)d_in[9];
    const float* init_ew  = (const float*)d_in[10];
    const float* init_eb  = (const float*)d_in[11];
    const float* init_pw  = (const float*)d_in[12];
    const float* init_pb  = (const float*)d_in[13];
    const float* send_w1  = (const float*)d_in[14];
    const float* send_b1  = (const float*)d_in[15];
    const float* send_w2  = (const float*)d_in[16];
    const float* send_b2  = (const float*)d_in[17];
    const float* r_oe_w1  = (const float*)d_in[18];
    const float* r_oe_b1  = (const float*)d_in[19];
    const float* r_oe_w2  = (const float*)d_in[20];
    const float* r_oe_b2  = (const float*)d_in[21];
    const float* r_op_w1  = (const float*)d_in[22];
    const float* r_op_b1  = (const float*)d_in[23];
    const float* r_op_w2  = (const float*)d_in[24];
    const float* r_op_b2  = (const float*)d_in[25];
    const float* r_ie_w1  = (const float*)d_in[26];
    const float* r_ie_b1  = (const float*)d_in[27];
    const float* r_ie_w2  = (const float*)d_in[28];
    const float* r_ie_b2  = (const float*)d_in[29];
    const float* r_ip_w1  = (const float*)d_in[30];
    const float* r_ip_b1  = (const float*)d_in[31];
    const float* r_ip_w2  = (const float*)d_in[32];
    const float* r_ip_b2  = (const float*)d_in[33];
    const float* gru_W    = (const float*)d_in[34];
    const float* gru_U    = (const float*)d_in[35];
    const float* gru_bW   = (const float*)d_in[36];
    const float* gru_bU   = (const float*)d_in[37];
    const float* out_w1   = (const float*)d_in[38];
    const float* out_b1   = (const float*)d_in[39];
    const float* out_w2   = (const float*)d_in[40];
    const float* out_b2   = (const float*)d_in[41];

    float* entlg = (float*)d_out;                    // [512, 151]
    float* prdlg = (float*)d_out + (long)NN * CE;    // [4096, 51]

    // ---- workspace (fp32), ~164 MB (< 176 MB proven available) ----
    float* p = (float*)d_ws;
    auto alloc = [&](long n) { float* q = p; p += n; return q; };
    float* oe    = alloc((long)CE * D);
    float* op    = alloc((long)CR * D);
    float* ie    = alloc((long)NN * D);
    float* ipn   = alloc((long)RR * D);
    float* E_ent = alloc((long)NN * CE);
    float* E_prd = alloc((long)RR * CR);
    float* m_oe  = alloc((long)CE * D4);
    float* m_op  = alloc((long)CR * D4);
    float* m_ie  = alloc((long)NN * D4);
    float* m_ip  = alloc((long)RR * D4);
    float* rc_oe = alloc((long)CE * MO);
    float* rc_op = alloc((long)CR * MO);
    float* rc_ie = alloc((long)NN * MI);
    float* rc_ip = alloc((long)RR * MI);
    float* msg   = alloc((long)NT * D);       // concatenated recv-MLP outputs
    float* gbuf  = alloc((long)NT * 3 * D);   // GRU gates; also carved for hid/fout
    float* zbuf  = alloc((long)NT * D);
    float* rbuf  = alloc((long)NT * D);
    size_t need = (size_t)(p - (float*)d_ws) * sizeof(float);
    if (ws_size < need) return;

    // Phase-local carves from gbuf (gbuf only live during the GRU phase):
    float* hidS = gbuf;                        // send L1 out, [NT, 512]
    float* hidA = gbuf;                        // recv L1 {oe,op}, [202, 1792]
    float* hidB = gbuf + (long)(CE + CR) * MO; // recv L1 {ie,ip}, [4608, 768]
    float* hidO = gbuf;                        // out L1, [NT, 1024]
    float* fout = gbuf + (long)NT * D;         // out L2, [NT, 1024]

    auto grid1 = [](long n) { return dim3((unsigned)((n + 255) / 256)); };

    auto gemm = [&](const float* A, int lda, int tA, const float* B, int ldb, int tB,
                    const float* bias, float* C, int ldc, int M, int Nn, int Kk, int act, int accum) {
        if (M >= 2048) {
            dim3 g((Nn + 63) / 64, (M + 127) / 128, 1);
            gemm_kernel<128><<<g, 256, 0, stream>>>(A, lda, tA, 0, B, ldb, tB, 0,
                                                    bias, C, ldc, 0, M, Nn, Kk, act, accum);
        } else {
            dim3 g((Nn + 63) / 64, (M + 63) / 64, 1);
            gemm_kernel<64><<<g, 256, 0, stream>>>(A, lda, tA, 0, B, ldb, tB, 0,
                                                   bias, C, ldc, 0, M, Nn, Kk, act, accum);
        }
    };

    auto setg = [](GG& q, int g, const float* A, const float* B, float* C, const float* bias,
                   int M, int K, int lda, int ldb, int ldc, long sAz) {
        q.A[g] = A; q.B[g] = B; q.C[g] = C; q.bias[g] = bias;
        q.M[g] = M; q.K[g] = K; q.lda[g] = lda; q.ldb[g] = ldb; q.ldc[g] = ldc; q.sAz[g] = sAz;
    };
    auto gg = [&](GG& q, int N, int nz, int transA, int act, int accum, long sBz, long zColC) {
        q.transA = transA; q.act = act; q.accum = accum; q.sBz = sBz; q.zColC = zColC;
        int tiles = 0; q.tOff[0] = 0;
        for (int g = 0; g < 4; ++g) {
            if (q.M[g] > 0) tiles += (q.M[g] + 127) / 128;
            q.tOff[g + 1] = tiles;
        }
        dim3 grid(N / 64, tiles, nz);
        gemm_grouped<<<grid, 256, 0, stream>>>(q, N);
    };

    const float* nodeP[4] = {oe, op, ie, ipn};
    const int    nodeM[4] = {CE, CR, NN, RR};
    const int    nodeOff[4] = {OF_OE, OF_OP, OF_IE, OF_IP};

    // ---- init ----
    copy_f<<<grid1((long)NN * D), 256, 0, stream>>>(roi, ie, NN * D);
    copy_f<<<grid1((long)RR * D), 256, 0, stream>>>(uni, ipn, RR * D);
    gemm(emb_ent, EMB, 0, init_ew, D, 0, init_eb, oe, D, CE, D, EMB, 0, 0);
    gemm(emb_prd, EMB, 0, init_pw, D, 0, init_pb, op, D, CR, D, EMB, 0, 0);
    copy_f<<<grid1((long)NN * CE), 256, 0, stream>>>(obj_log, entlg, NN * CE);
    softmax_rows<<<NN, 256, 0, stream>>>(entlg, E_ent, CE);
    zero_f<<<grid1((long)RR * CR), 256, 0, stream>>>(E_prd, RR * CR);

    for (int t = 0; t < T; ++t) {
        // ---- send MLPs: 2 grouped launches (4 types each) ----
        {
            GG q{};
            for (int g = 0; g < 4; ++g)
                setg(q, g, nodeP[g], send_w1 + (long)g * D * D2, hidS + (long)nodeOff[g] * D2,
                     send_b1 + g * D2, nodeM[g], D, D, D2, D2, 0);
            gg(q, D2, 1, 0, 1, 0, 0, 0);
        }
        {
            GG q{};
            float* mT[4] = {m_oe, m_op, m_ie, m_ip};
            for (int g = 0; g < 4; ++g)
                setg(q, g, hidS + (long)nodeOff[g] * D2, send_w2 + (long)g * D2 * D4, mT[g],
                     send_b2 + g * D4, nodeM[g], D2, D2, D4, D4, 0);
            gg(q, D4, 1, 0, 1, 0, 0, 0);
        }

        // ---- receive ----
        {   // rcv_oe cols [0:3*D4): e2e; [3*D4:6*D4): p2e  (transA, z = 3 adjacency slices)
            GG q{};
            setg(q, 0, adj_e2e, m_oe, rc_oe,          nullptr, CE, CE, CE, D4, MO, (long)CE * CE);
            setg(q, 1, adj_p2e, m_op, rc_oe + 3 * D4, nullptr, CE, CR, CE, D4, MO, (long)CR * CE);
            gg(q, D4, K3, 1, 0, 0, 0, D4);
        }
        {   // rcv_op cols: e2p | p2p
            GG q{};
            setg(q, 0, adj_e2p, m_oe, rc_op,          nullptr, CR, CE, CR, D4, MO, (long)CE * CR);
            setg(q, 1, adj_p2p, m_op, rc_op + 3 * D4, nullptr, CR, CR, CR, D4, MO, (long)CR * CR);
            gg(q, D4, K3, 1, 0, 0, 0, D4);
        }
        {   // bridges (transposed): E_ent^T m_ie -> rc_oe tail; E_prd^T m_ip -> rc_op tail
            GG q{};
            setg(q, 0, E_ent, m_ie, rc_oe + 6 * D4, nullptr, CE, NN, CE, D4, MO, 0);
            setg(q, 1, E_prd, m_ip, rc_op + 6 * D4, nullptr, CR, RR, CR, D4, MO, 0);
            gg(q, D4, 1, 1, 0, 0, 0, 0);
        }
        edge_scatter_sum<<<NN, 256, 0, stream>>>(m_ip, pair, rc_ie, RR);
        gather_msgs<<<grid1((long)RR * D4), 256, 0, stream>>>(m_ie, pair, rc_ip, RR);
        {   // bridges (forward): E_ent @ m_oe -> rc_ie tail; E_prd @ m_op -> rc_ip tail
            GG q{};
            setg(q, 0, E_ent, m_oe, rc_ie + 2 * D4, nullptr, NN, CE, CE, D4, MI, 0);
            setg(q, 1, E_prd, m_op, rc_ip + 2 * D4, nullptr, RR, CR, CR, D4, MI, 0);
            gg(q, D4, 1, 0, 0, 0, 0, 0);
        }

        // ---- recv MLPs: grouped pairs (same K within pair) ----
        {   // L1 {oe,op}: K=N=1792
            GG q{};
            setg(q, 0, rc_oe, r_oe_w1, hidA,                 r_oe_b1, CE, MO, MO, MO, MO, 0);
            setg(q, 1, rc_op, r_op_w1, hidA + (long)CE * MO, r_op_b1, CR, MO, MO, MO, MO, 0);
            gg(q, MO, 1, 0, 1, 0, 0, 0);
        }
        {   // L2 {oe,op}: -> msg rows
            GG q{};
            setg(q, 0, hidA,                 r_oe_w2, msg + (long)OF_OE * D, r_oe_b2, CE, MO, MO, D, D, 0);
            setg(q, 1, hidA + (long)CE * MO, r_op_w2, msg + (long)OF_OP * D, r_op_b2, CR, MO, MO, D, D, 0);
            gg(q, D, 1, 0, 1, 0, 0, 0);
        }
        {   // L1 {ie,ip}: K=N=768
            GG q{};
            setg(q, 0, rc_ie, r_ie_w1, hidB,                 r_ie_b1, NN, MI, MI, MI, MI, 0);
            setg(q, 1, rc_ip, r_ip_w1, hidB + (long)NN * MI, r_ip_b1, RR, MI, MI, MI, MI, 0);
            gg(q, MI, 1, 0, 1, 0, 0, 0);
        }
        {   // L2 {ie,ip}
            GG q{};
            setg(q, 0, hidB,                 r_ie_w2, msg + (long)OF_IE * D, r_ie_b2, NN, MI, MI, D, D, 0);
            setg(q, 1, hidB + (long)NN * MI, r_ip_w2, msg + (long)OF_IP * D, r_ip_b2, RR, MI, MI, D, D, 0);
            gg(q, D, 1, 0, 1, 0, 0, 0);
        }

        // ---- GRU: all 4 types per launch, gates via grid.z ----
        {   // gbuf[:, z*D:(z+1)*D] = msg @ W[type][z], z = 0..2
            GG q{};
            for (int g = 0; g < 4; ++g)
                setg(q, g, msg + (long)nodeOff[g] * D, gru_W + (long)g * 3 * D * D,
                     gbuf + (long)nodeOff[g] * 3 * D, nullptr, nodeM[g], D, D, D, 3 * D, 0);
            gg(q, D, 3, 0, 0, 0, (long)D * D, D);
        }
        {   // gbuf[:, z*D:(z+1)*D] += X @ U[type][z], z = 0..1
            GG q{};
            for (int g = 0; g < 4; ++g)
                setg(q, g, nodeP[g], gru_U + (long)g * 3 * D * D,
                     gbuf + (long)nodeOff[g] * 3 * D, nullptr, nodeM[g], D, D, D, 3 * D, 0);
            gg(q, D, 2, 0, 0, 1, (long)D * D, D);
        }
        gru_ew1_g<<<grid1((long)NT * D), 256, 0, stream>>>(gbuf, gru_bW, gru_bU,
                                                           oe, op, ie, ipn, zbuf, rbuf, NT * D);
        {   // gbuf[:, 2D:3D] += rbuf @ U[type][2]
            GG q{};
            for (int g = 0; g < 4; ++g)
                setg(q, g, rbuf + (long)nodeOff[g] * D, gru_U + (long)g * 3 * D * D + 2 * (long)D * D,
                     gbuf + (long)nodeOff[g] * 3 * D + 2 * D, nullptr, nodeM[g], D, D, D, 3 * D, 0);
            gg(q, D, 1, 0, 0, 1, 0, 0);
        }
        gru_ew2_g<<<grid1((long)NT * D), 256, 0, stream>>>(gbuf, gru_bW, gru_bU,
                                                           oe, op, ie, ipn, zbuf, NT * D);

        // ---- output projections (grouped, weight order: ie, oe, ip, op) ----
        const float* outA[4] = {ie, oe, ipn, op};
        const int    outM[4] = {NN, CE, RR, CR};
        const long   outOff[4] = {0, NN, NN + CE, NN + CE + RR};
        {
            GG q{};
            for (int g = 0; g < 4; ++g)
                setg(q, g, outA[g], out_w1 + (long)g * D * D, hidO + outOff[g] * D,
                     out_b1 + g * D, outM[g], D, D, D, D, 0);
            gg(q, D, 1, 0, 1, 0, 0, 0);
        }
        {
            GG q{};
            for (int g = 0; g < 4; ++g)
                setg(q, g, hidO + outOff[g] * D, out_w2 + (long)g * D * D, fout + outOff[g] * D,
                     out_b2 + g * D, outM[g], D, D, D, D, 0);
            gg(q, D, 1, 0, 0, 0, 0, 0);
        }
        // logits: X_img @ X_ont^T (transB), then softmax bridges
        gemm(fout + outOff[0] * D, D, 0, fout + outOff[1] * D, D, 1, nullptr,
             entlg, CE, NN, CE, D, 0, 0);
        gemm(fout + outOff[2] * D, D, 0, fout + outOff[3] * D, D, 1, nullptr,
             prdlg, CR, RR, CR, D, 0, 0);
        softmax_rows<<<NN, 256, 0, stream>>>(entlg, E_ent, CE);
        softmax_rows<<<RR, 256, 0, stream>>>(prdlg, E_prd, CR);
    }
    // outputs in d_out: ent_logits [512,151] then pred_logits [4096,51], fp32
}